// Round 6
// baseline (833.074 us; speedup 1.0000x reference)
//
#include <hip/hip_runtime.h>

// Viterbi CRF decode: B=512, T=512, K=64.
// Round 6: round-5 fused kernel with the asm pin fixed: gfx950 inline asm
// rejects tied AGGREGATE operands (float4 "+v" -> "tied indirect register
// inputs"), so the 64 transition values are 64 named SCALAR floats pinned by
// four asm statements of 16 tied scalar "+v" operands each. Combined with
// amdgpu_waves_per_eu(1,1) (512-VGPR budget; we only have 2 blocks/CU so
// occupancy is moot) this finally forces trans column residency -- rounds
// 1/3 demoted it to scratch (VGPR=64, phantom LDS + 2.2e7 conflicts) and
// round 4 re-sank the loads into the loop (VGPR=44, 437us).
//  - Wave 0: sync-free forward; score broadcast via v_readlane; history
//    written to LDS (32 KB), never HBM (rounds 2-4's ~85us residual was the
//    2nd launch + 33 MB hist round-trip).
//  - All 4 waves: hypothesis-parallel backtrace (wave w chases chunks
//    {w,w+4}, lane = entry hypothesis), 8-map composition, shuffle emit.
// fp association (score+trans)+emit exact -> bitwise-identical scores;
// strict-> chains over ascending i merged ascending = jnp.argmax
// first-index tie rule. d_ws unused.

#define TT 512
#define BB 512
#define KK 64
#define NEG_INF (-3.402823466e38f)

__device__ __forceinline__ float rl(float v, int lane) {
    return __uint_as_float(__builtin_amdgcn_readlane(__float_as_uint(v), lane));
}

__global__ __launch_bounds__(256)
__attribute__((amdgpu_waves_per_eu(1, 1)))
void viterbi_fused(
    const float* __restrict__ emissions,   // [B,T,K]
    const int* __restrict__ attn_mask,     // [B,T]
    const float* __restrict__ start_t,     // [K]
    const float* __restrict__ end_t,       // [K]
    const float* __restrict__ trans,       // [K,K]
    int* __restrict__ out)                 // [B,T] int32
{
    const int b   = blockIdx.x;
    const int tid = threadIdx.x;
    const int w   = __builtin_amdgcn_readfirstlane(tid >> 6);  // wave id
    const int l   = tid & 63;

    __shared__ unsigned char sh_hist[TT * KK];   // rows 0..510 used (32 KB)
    __shared__ unsigned char maps[8][KK];        // chunk exit maps
    __shared__ int entries[8];
    __shared__ int sh_best;

    const int* mb = attn_mask + (size_t)b * TT;

    if (w == 0) {
        // ---------------- forward pass (single wave, sync-free) ----------
        const int j = l;
        const float* eb = emissions + (size_t)b * TT * KK;

        // trans column j: 64 named scalars (T<i> = trans[i][j])
#define L(i) float T##i = trans[(i) * KK + j];
        L(0)  L(1)  L(2)  L(3)  L(4)  L(5)  L(6)  L(7)
        L(8)  L(9)  L(10) L(11) L(12) L(13) L(14) L(15)
        L(16) L(17) L(18) L(19) L(20) L(21) L(22) L(23)
        L(24) L(25) L(26) L(27) L(28) L(29) L(30) L(31)
        L(32) L(33) L(34) L(35) L(36) L(37) L(38) L(39)
        L(40) L(41) L(42) L(43) L(44) L(45) L(46) L(47)
        L(48) L(49) L(50) L(51) L(52) L(53) L(54) L(55)
        L(56) L(57) L(58) L(59) L(60) L(61) L(62) L(63)
#undef L
        // pin into VGPRs above the loop (scalar tied operands are supported)
        asm volatile("" :
            "+v"(T0),  "+v"(T1),  "+v"(T2),  "+v"(T3),
            "+v"(T4),  "+v"(T5),  "+v"(T6),  "+v"(T7),
            "+v"(T8),  "+v"(T9),  "+v"(T10), "+v"(T11),
            "+v"(T12), "+v"(T13), "+v"(T14), "+v"(T15));
        asm volatile("" :
            "+v"(T16), "+v"(T17), "+v"(T18), "+v"(T19),
            "+v"(T20), "+v"(T21), "+v"(T22), "+v"(T23),
            "+v"(T24), "+v"(T25), "+v"(T26), "+v"(T27),
            "+v"(T28), "+v"(T29), "+v"(T30), "+v"(T31));
        asm volatile("" :
            "+v"(T32), "+v"(T33), "+v"(T34), "+v"(T35),
            "+v"(T36), "+v"(T37), "+v"(T38), "+v"(T39),
            "+v"(T40), "+v"(T41), "+v"(T42), "+v"(T43),
            "+v"(T44), "+v"(T45), "+v"(T46), "+v"(T47));
        asm volatile("" :
            "+v"(T48), "+v"(T49), "+v"(T50), "+v"(T51),
            "+v"(T52), "+v"(T53), "+v"(T54), "+v"(T55),
            "+v"(T56), "+v"(T57), "+v"(T58), "+v"(T59),
            "+v"(T60), "+v"(T61), "+v"(T62), "+v"(T63));

        float score = start_t[j] + eb[j];

        // 2-deep prefetch rings
        float e0 = eb[KK + j];
        float e1 = eb[2*KK + j];
        int   m0 = mb[1];
        int   m1 = mb[2];

        for (int t = 1; t < TT; ++t) {
            float e = e0; e0 = e1;
            int   m = m0; m0 = m1;
            int tn = (t + 2 < TT) ? (t + 2) : (TT - 1);
            e1 = eb[(size_t)tn * KK + j];
            m1 = mb[tn];

            // 4 strict-> chains over ascending i, merged ascending:
            // reproduces jnp.argmax first-index tie-break exactly.
            float bv0 = NEG_INF, bv1 = NEG_INF, bv2 = NEG_INF, bv3 = NEG_INF;
            int   bi0 = 0, bi1 = 16, bi2 = 32, bi3 = 48;

#define CELL(cn, idx, tv)                                               \
            { float s = rl(score, (idx));                               \
              float cand = (s + (tv)) + e;  /* exact ref association */ \
              if (cand > bv##cn) { bv##cn = cand; bi##cn = (idx); } }
#define ROW(q0, q1, q2, q3)                                             \
            CELL(0, q0, T##q0) CELL(1, q1, T##q1)                       \
            CELL(2, q2, T##q2) CELL(3, q3, T##q3)

            ROW(0, 16, 32, 48)  ROW(1, 17, 33, 49)
            ROW(2, 18, 34, 50)  ROW(3, 19, 35, 51)
            ROW(4, 20, 36, 52)  ROW(5, 21, 37, 53)
            ROW(6, 22, 38, 54)  ROW(7, 23, 39, 55)
            ROW(8, 24, 40, 56)  ROW(9, 25, 41, 57)
            ROW(10, 26, 42, 58) ROW(11, 27, 43, 59)
            ROW(12, 28, 44, 60) ROW(13, 29, 45, 61)
            ROW(14, 30, 46, 62) ROW(15, 31, 47, 63)
#undef ROW
#undef CELL

            float best = bv0; int bi = bi0;
            if (bv1 > best) { best = bv1; bi = bi1; }
            if (bv2 > best) { best = bv2; bi = bi2; }
            if (bv3 > best) { best = bv3; bi = bi3; }

            sh_hist[(t-1)*KK + j] = (unsigned char)bi;
            score = m ? best : score;   // freeze past sequence end
        }

        // final argmax (uniform via readlane; lane 0 publishes)
        float fin = score + end_t[j];
        float bvf = rl(fin, 0); int btg = 0;
#pragma unroll
        for (int k = 1; k < KK; ++k) {
            float v = rl(fin, k);
            if (v > bvf) { bvf = v; btg = k; }
        }
        if (l == 0) sh_best = btg;
    }

    __syncthreads();

    // ---------------- backtrace (all 4 waves, hypothesis-parallel) -------
    // wave w chases chunks c = w, w+4; lane l = entry hypothesis tag.
    unsigned int rec_reg[2][16];
#pragma unroll
    for (int cc = 0; cc < 2; ++cc) {
        const int c = w + cc * 4;
        // mask bits for rows r = c*64 + i (row r uses attn_mask[b][r+1])
        int r_l = c * KK + l;
        int mreg = (r_l <= TT - 2) ? mb[r_l + 1] : 0;
        unsigned long long mb64 = __ballot(mreg != 0);

        int tag = l;
#pragma unroll
        for (int k = 0; k < 16; ++k) rec_reg[cc][k] = 0;
#pragma unroll
        for (int i = 63; i >= 0; --i) {
            // hist[r][tag], r = c*64+i (row 511 hop has mask bit 0 -> dead)
            int v = (int)sh_hist[c * 4096 + i * KK + tag];
            int mbit = (int)((mb64 >> i) & 1ull);   // wave-uniform
            tag = mbit ? v : tag;
            rec_reg[cc][i >> 2] |= (unsigned int)tag << ((i & 3) * 8);
        }
        maps[c][l] = (unsigned char)tag;   // chunk exit for hypothesis l
    }
    __syncthreads();

    // compose the 8 chunk maps (serial, tiny)
    if (tid == 0) {
        int tg = sh_best;
        for (int c = 7; c >= 0; --c) {
            entries[c] = tg;        // true entry tag for chunk c
            tg = maps[c][tg];       // exit becomes entry of chunk c-1
        }
    }
    __syncthreads();

    // emit: broadcast the winning lane's record via 16 uniform shuffles
#pragma unroll
    for (int cc = 0; cc < 2; ++cc) {
        const int c = w + cc * 4;
        const int e = entries[c];
        unsigned int myd = 0;
#pragma unroll
        for (int k = 0; k < 16; ++k) {
            unsigned int dv = (unsigned int)__shfl((int)rec_reg[cc][k], e);
            if ((l >> 2) == k) myd = dv;
        }
        int v = (int)((myd >> ((l & 3) * 8)) & 0xFFu);
        out[(size_t)b * TT + c * KK + l] = v;
    }
}

extern "C" void kernel_launch(void* const* d_in, const int* in_sizes, int n_in,
                              void* d_out, int out_size, void* d_ws, size_t ws_size,
                              hipStream_t stream) {
    const float* emissions = (const float*)d_in[0];
    const int* attn_mask   = (const int*)d_in[1];
    const float* start_t   = (const float*)d_in[2];
    const float* end_t     = (const float*)d_in[3];
    const float* trans     = (const float*)d_in[4];
    int* out = (int*)d_out;

    viterbi_fused<<<BB, 256, 0, stream>>>(emissions, attn_mask, start_t, end_t,
                                          trans, out);
}

// Round 7
// 474.681 us; speedup vs baseline: 1.7550x; 1.7550x over previous
//
#include <hip/hip_runtime.h>

// Viterbi CRF decode: B=512, T=512, K=64.
// Round 7: single-wave fused blocks (64 threads), full concurrency.
//  - Round 6's waves_per_eu(1,1) + 256-thr blocks forced 1 block/CU -> 512
//    blocks ran as 2 sequential rounds (778 = 2x389us). With 64-thr blocks
//    the (1,1) cap makes HW spread waves 1/SIMD: 2 blocks/CU on 2 different
//    SIMDs, all 512 concurrent.
//  - Score broadcast via LDS ds_read (same-address = conflict-free
//    broadcast, runs on LDS pipe overlapping VALU) replaces v_readlane:
//    kills the per-step 64x VALU->SGPR-read hazard chains suspected of the
//    1830-vs-800 cyc/step gap. trans column stays pinned in VGPRs (round-6
//    mechanism, proven by VGPR_Count=132).
//  - Backtrace on the same single wave: pass 1 chases all 8 chunks' 64
//    entry hypotheses interleaved (8 outstanding LDS dependent chains),
//    compose 8 chunk maps (uniform), pass 2 re-chases the true path with 8
//    parallel lanes writing path bytes to LDS, then coalesced emit.
// fp association (score+trans)+emit exact -> scores bitwise-identical to
// reference; strict-> chains over ascending i merged ascending = jnp.argmax
// first-index tie rule. d_ws unused.

#define TT 512
#define BB 512
#define KK 64
#define NEG_INF (-3.402823466e38f)

__global__ __launch_bounds__(64)
__attribute__((amdgpu_waves_per_eu(1, 1)))
void viterbi_fused(
    const float* __restrict__ emissions,   // [B,T,K]
    const int* __restrict__ attn_mask,     // [B,T]
    const float* __restrict__ start_t,     // [K]
    const float* __restrict__ end_t,       // [K]
    const float* __restrict__ trans,       // [K,K]
    int* __restrict__ out)                 // [B,T] int32
{
    const int b = blockIdx.x;
    const int j = threadIdx.x;             // lane id (wave64)

    __shared__ float s_score[KK];                 // 256 B score broadcast
    __shared__ unsigned char sh_hist[TT * KK];    // 32 KB (rows 0..510)
    __shared__ unsigned char s_maps[8 * KK];      // chunk exit maps
    __shared__ unsigned char s_path[TT];          // decoded path bytes
    __shared__ unsigned long long s_mb64[8];      // per-chunk mask ballots
    __shared__ int s_ent[8];                      // chunk entry tags

    const float* eb = emissions + (size_t)b * TT * KK;
    const int*   mb = attn_mask + (size_t)b * TT;

    // ---- trans column j: 64 named scalars pinned into VGPRs ----
#define L(i) float T##i = trans[(i) * KK + j];
    L(0)  L(1)  L(2)  L(3)  L(4)  L(5)  L(6)  L(7)
    L(8)  L(9)  L(10) L(11) L(12) L(13) L(14) L(15)
    L(16) L(17) L(18) L(19) L(20) L(21) L(22) L(23)
    L(24) L(25) L(26) L(27) L(28) L(29) L(30) L(31)
    L(32) L(33) L(34) L(35) L(36) L(37) L(38) L(39)
    L(40) L(41) L(42) L(43) L(44) L(45) L(46) L(47)
    L(48) L(49) L(50) L(51) L(52) L(53) L(54) L(55)
    L(56) L(57) L(58) L(59) L(60) L(61) L(62) L(63)
#undef L
    asm volatile("" :
        "+v"(T0),  "+v"(T1),  "+v"(T2),  "+v"(T3),
        "+v"(T4),  "+v"(T5),  "+v"(T6),  "+v"(T7),
        "+v"(T8),  "+v"(T9),  "+v"(T10), "+v"(T11),
        "+v"(T12), "+v"(T13), "+v"(T14), "+v"(T15));
    asm volatile("" :
        "+v"(T16), "+v"(T17), "+v"(T18), "+v"(T19),
        "+v"(T20), "+v"(T21), "+v"(T22), "+v"(T23),
        "+v"(T24), "+v"(T25), "+v"(T26), "+v"(T27),
        "+v"(T28), "+v"(T29), "+v"(T30), "+v"(T31));
    asm volatile("" :
        "+v"(T32), "+v"(T33), "+v"(T34), "+v"(T35),
        "+v"(T36), "+v"(T37), "+v"(T38), "+v"(T39),
        "+v"(T40), "+v"(T41), "+v"(T42), "+v"(T43),
        "+v"(T44), "+v"(T45), "+v"(T46), "+v"(T47));
    asm volatile("" :
        "+v"(T48), "+v"(T49), "+v"(T50), "+v"(T51),
        "+v"(T52), "+v"(T53), "+v"(T54), "+v"(T55),
        "+v"(T56), "+v"(T57), "+v"(T58), "+v"(T59),
        "+v"(T60), "+v"(T61), "+v"(T62), "+v"(T63));

    // ---------------- forward pass ----------------
    float score = start_t[j] + eb[j];
    s_score[j] = score;                    // same-wave LDS ops are ordered

    float e0 = eb[KK + j];
    float e1 = eb[2*KK + j];
    int   m0 = mb[1];
    int   m1 = mb[2];

    for (int t = 1; t < TT; ++t) {
        float e = e0; e0 = e1;
        int   m = m0; m0 = m1;
        int tn = (t + 2 < TT) ? (t + 2) : (TT - 1);
        e1 = eb[(size_t)tn * KK + j];
        m1 = mb[tn];

        // broadcast reads of the score vector (uniform address per read)
        float sv[KK];
#pragma unroll
        for (int i = 0; i < KK; ++i) sv[i] = s_score[i];

        // 4 strict-> chains over ascending i, merged ascending:
        // reproduces jnp.argmax first-index tie-break exactly.
        float bv0 = NEG_INF, bv1 = NEG_INF, bv2 = NEG_INF, bv3 = NEG_INF;
        int   bi0 = 0, bi1 = 16, bi2 = 32, bi3 = 48;

#define CELL(cn, idx)                                                   \
        { float cand = (sv[idx] + T##idx) + e;  /* exact ref assoc */   \
          if (cand > bv##cn) { bv##cn = cand; bi##cn = (idx); } }
#define ROW(q0, q1, q2, q3)                                             \
        CELL(0, q0) CELL(1, q1) CELL(2, q2) CELL(3, q3)

        ROW(0, 16, 32, 48)  ROW(1, 17, 33, 49)
        ROW(2, 18, 34, 50)  ROW(3, 19, 35, 51)
        ROW(4, 20, 36, 52)  ROW(5, 21, 37, 53)
        ROW(6, 22, 38, 54)  ROW(7, 23, 39, 55)
        ROW(8, 24, 40, 56)  ROW(9, 25, 41, 57)
        ROW(10, 26, 42, 58) ROW(11, 27, 43, 59)
        ROW(12, 28, 44, 60) ROW(13, 29, 45, 61)
        ROW(14, 30, 46, 62) ROW(15, 31, 47, 63)
#undef ROW
#undef CELL

        float best = bv0; int bi = bi0;
        if (bv1 > best) { best = bv1; bi = bi1; }
        if (bv2 > best) { best = bv2; bi = bi2; }
        if (bv3 > best) { best = bv3; bi = bi3; }

        sh_hist[(t-1)*KK + j] = (unsigned char)bi;
        score = m ? best : score;          // freeze past sequence end
        s_score[j] = score;                // publish for next step
    }

    // final scores + uniform argmax via broadcast reads
    float fin = score + end_t[j];
    s_score[j] = fin;
    float bvf = s_score[0]; int btg = 0;
#pragma unroll
    for (int k = 1; k < KK; ++k) {
        float v = s_score[k];
        if (v > bvf) { bvf = v; btg = k; }
    }
    // btg is wave-uniform (computed from broadcast values)

    // ---------------- backtrace (same wave) ----------------
    // pass 1: chunk exit maps — 8 chunks chased in parallel (interleaved
    // dependent LDS chains), lane = entry hypothesis.
    unsigned long long bm[8];
#pragma unroll
    for (int c = 0; c < 8; ++c) {
        int r_l = c * KK + j;
        int mreg = (r_l <= TT - 2) ? mb[r_l + 1] : 0;
        bm[c] = __ballot(mreg != 0);
        if (j == 0) s_mb64[c] = bm[c];
    }
    int tgp[8];
#pragma unroll
    for (int c = 0; c < 8; ++c) tgp[c] = j;
    for (int i = 63; i >= 0; --i) {
        int vv[8];
#pragma unroll
        for (int c = 0; c < 8; ++c)
            vv[c] = (int)sh_hist[c * 4096 + i * KK + tgp[c]];
#pragma unroll
        for (int c = 0; c < 8; ++c) {
            int mbit = (int)((bm[c] >> i) & 1ull);
            tgp[c] = mbit ? vv[c] : tgp[c];
        }
    }
#pragma unroll
    for (int c = 0; c < 8; ++c) s_maps[c * KK + j] = (unsigned char)tgp[c];

    // compose chunk maps (uniform on all lanes; broadcast reads)
    int ent[8];
    {
        int tg = btg;
#pragma unroll
        for (int c = 7; c >= 0; --c) {
            ent[c] = tg;
            tg = (int)s_maps[c * KK + tg];
        }
    }
    if (j == 0) {
        s_ent[0] = ent[0]; s_ent[1] = ent[1]; s_ent[2] = ent[2];
        s_ent[3] = ent[3]; s_ent[4] = ent[4]; s_ent[5] = ent[5];
        s_ent[6] = ent[6]; s_ent[7] = ent[7];
    }

    // pass 2: true-path re-chase, 8 lanes in parallel (lane = chunk)
    if (j < 8) {
        const int c = j;
        unsigned long long mbits = s_mb64[c];
        int tg2 = s_ent[c];
        for (int i = 63; i >= 0; --i) {
            int v = (int)sh_hist[c * 4096 + i * KK + tg2];
            int mbit = (int)((mbits >> i) & 1ull);
            tg2 = mbit ? v : tg2;
            s_path[c * KK + i] = (unsigned char)tg2;
            // note: (c=7,i=63) -> row 511: mask bit is 0, tg2 == btg there.
        }
    }
    if (j == 0) s_path[TT - 1] = (unsigned char)btg;  // explicit (same value)

    // emit
#pragma unroll
    for (int c = 0; c < 8; ++c)
        out[(size_t)b * TT + c * KK + j] = (int)s_path[c * KK + j];
}

extern "C" void kernel_launch(void* const* d_in, const int* in_sizes, int n_in,
                              void* d_out, int out_size, void* d_ws, size_t ws_size,
                              hipStream_t stream) {
    const float* emissions = (const float*)d_in[0];
    const int* attn_mask   = (const int*)d_in[1];
    const float* start_t   = (const float*)d_in[2];
    const float* end_t     = (const float*)d_in[3];
    const float* trans     = (const float*)d_in[4];
    int* out = (int*)d_out;

    viterbi_fused<<<BB, KK, 0, stream>>>(emissions, attn_mask, start_t, end_t,
                                         trans, out);
}